// Round 4
// baseline (265.739 us; speedup 1.0000x reference)
//
#include <hip/hip_runtime.h>

// Problem: Embedding_6940667150787
//   idx:      [131072] int32 in [0, 198)
//   wordlist: [198, 512] float32
//   out:      [131072, 512] float32 = wordlist[idx] + positional_encoding
//
// PE: for j in 0..254: angle = i / 10000^(2j/512);
//     pe[i, 2j] = sin(angle), pe[i, 2j+1] = cos(angle); cols 510,511 = 0.
//
// R4 (= R3 with compile fix): HBM-write-bound (256 MiB out). Each thread:
// one float4-column x R=8 consecutive rows. exp2 freqs once/thread;
// Cody-Waite sincos for the base row; advance per row via exact rotation
// (4 FMA/pair). Nontemporal stores via clang native vector type
// (__builtin_nontemporal_store rejects HIP_vector_type float4).

#define L_TOTAL 131072
#define VEC_PER_ROW 128   // 512 floats / 4
#define R 8               // rows per thread

typedef float v4f __attribute__((ext_vector_type(4)));

__device__ __forceinline__ void sincos_fast(float a, float& s, float& c) {
    // Cody-Waite reduction by 2*pi (FMA), then HW transcendental
    // (input in REVOLUTIONS).
    const float INV2PI = 0.15915493667125702f;
    const float PI2_HI = 6.2831854820251465f;
    const float PI2_LO = -1.7484555314695172e-7f;
    float k = rintf(a * INV2PI);               // exact in fp32 (k <= ~2.1e4)
    float r = fmaf(-k, PI2_HI, a);
    r = fmaf(-k, PI2_LO, r);                   // |r| <= pi, err ~4e-7 rad
    float rev = r * INV2PI;
    s = __builtin_amdgcn_sinf(rev);            // v_sin_f32: sin(rev*2pi)
    c = __builtin_amdgcn_cosf(rev);            // v_cos_f32
}

__global__ __launch_bounds__(256) void embed_pe_kernel(
    const int* __restrict__ idx,
    const float* __restrict__ wordlist,
    float* __restrict__ out)
{
    int t  = blockIdx.x * 256 + threadIdx.x;   // 0 .. (L/R)*128 - 1
    int rb = t >> 7;                           // row-block (R rows)
    int cc = t & 127;                          // float4 column
    int i0 = rb * R;

    // Inverse frequencies for pair j0=2cc (cols 4cc,4cc+1), j1=2cc+1.
    const float K = 0.051905126483205076f;     // log2(10000) / 256
    float invf0 = exp2f(-(float)(2 * cc)     * K);
    float invf1 = exp2f(-(float)(2 * cc + 1) * K);

    // Base-row sin/cos + per-row rotation deltas.
    float s0, c0, s1, c1, sd0, cd0, sd1, cd1;
    sincos_fast((float)i0 * invf0, s0, c0);
    sincos_fast((float)i0 * invf1, s1, c1);
    sincos_fast(invf0, sd0, cd0);
    sincos_fast(invf1, sd1, cd1);

    if (cc == VEC_PER_ROW - 1) {               // j1==255 -> cols 510,511: PE=0
        s1 = 0.0f; c1 = 0.0f;                  // (0,0) is a fixed point of the
    }                                          // rotation below — stays zero.

    // Token ids for 8 rows: two int4 loads (i0 % 8 == 0).
    const int4* idx4 = (const int4*)idx;
    int4 ta = idx4[rb * 2];
    int4 tb = idx4[rb * 2 + 1];
    int tokens[R] = {ta.x, ta.y, ta.z, ta.w, tb.x, tb.y, tb.z, tb.w};

    v4f* out4 = (v4f*)out;
    const v4f* wl4 = (const v4f*)wordlist;

#pragma unroll
    for (int k = 0; k < R; ++k) {
        v4f w = wl4[tokens[k] * VEC_PER_ROW + cc];
        v4f o;
        o.x = w.x + s0;
        o.y = w.y + c0;
        o.z = w.z + s1;
        o.w = w.w + c1;
        __builtin_nontemporal_store(o, out4 + (i0 + k) * VEC_PER_ROW + cc);

        // rotate angles forward by one row: angle += invf
        float ns0 = fmaf(s0, cd0, c0 * sd0);
        float nc0 = fmaf(c0, cd0, -s0 * sd0);
        s0 = ns0; c0 = nc0;
        float ns1 = fmaf(s1, cd1, c1 * sd1);
        float nc1 = fmaf(c1, cd1, -s1 * sd1);
        s1 = ns1; c1 = nc1;
    }
}

extern "C" void kernel_launch(void* const* d_in, const int* in_sizes, int n_in,
                              void* d_out, int out_size, void* d_ws, size_t ws_size,
                              hipStream_t stream) {
    const int*   idx      = (const int*)d_in[0];
    const float* wordlist = (const float*)d_in[1];
    float*       out      = (float*)d_out;

    int total_threads = (L_TOTAL / R) * VEC_PER_ROW;  // 2,097,152
    int block = 256;
    int grid = total_threads / block;                 // 8,192 blocks
    embed_pe_kernel<<<grid, block, 0, stream>>>(idx, wordlist, out);
}